// Round 1
// baseline (347.507 us; speedup 1.0000x reference)
//
#include <hip/hip_runtime.h>
#include <math.h>

#define INPUT_SIZE 32768
#define FILTER_LEN 8192
#define FULL_LEN   40960   // 40959 real conv outputs + 1 structural zero
#define NUM_CLASSES 512
#define TOTAL_LEN  65536

// ---------------- reduction helpers ----------------
__device__ __forceinline__ float waveReduceSum(float v) {
#pragma unroll
  for (int o = 32; o > 0; o >>= 1) v += __shfl_down(v, o, 64);
  return v;
}
__device__ __forceinline__ float waveReduceMax(float v) {
#pragma unroll
  for (int o = 32; o > 0; o >>= 1) v = fmaxf(v, __shfl_down(v, o, 64));
  return v;
}

// ---------------- conv: split-K partial convolution ----------------
// f[j] = sum_k w[k] * v[j-k], v zero outside [0, INPUT_SIZE)
// block = (jtile, kchunk): TO=1024 outputs, KC=512 taps. 256 thr, 4 outputs/thr.
__global__ __launch_bounds__(256) void conv_kernel(
    const float* __restrict__ v, const float* __restrict__ w,
    float* __restrict__ partial)
{
  constexpr int TO = 1024, KC = 512, NKS = FILTER_LEN / KC; // NKS = 16
  __shared__ float lv[TO + KC]; // 1536 floats
  const int jt = blockIdx.x / NKS;
  const int ks = blockIdx.x % NKS;
  const int jb = jt * TO, kc = ks * KC;
  const int wb = jb - kc - (KC - 1); // window covers v[wb .. wb+1535]
  for (int s = threadIdx.x; s < TO + KC; s += 256) {
    int idx = wb + s;
    lv[s] = (idx >= 0 && idx < INPUT_SIZE) ? v[idx] : 0.0f;
  }
  __syncthreads();
  const int t = threadIdx.x;
  const float4* lv4 = reinterpret_cast<const float4*>(lv);
  // window regs cover lds float idx [4t+508-4g, 4t+516-4g)
  float4 lo = lv4[t + (KC / 4 - 1)]; // t+127
  float4 hi = lv4[t + (KC / 4)];     // t+128
  float a0 = 0.f, a1 = 0.f, a2 = 0.f, a3 = 0.f;
  const float* wp = w + kc;
  for (int g = 0; g < KC / 4 - 1; ++g) {
    const float w0 = wp[4 * g + 0], w1 = wp[4 * g + 1],
                w2 = wp[4 * g + 2], w3 = wp[4 * g + 3];
    a0 = fmaf(w0, lo.w, a0); a1 = fmaf(w0, hi.x, a1); a2 = fmaf(w0, hi.y, a2); a3 = fmaf(w0, hi.z, a3);
    a0 = fmaf(w1, lo.z, a0); a1 = fmaf(w1, lo.w, a1); a2 = fmaf(w1, hi.x, a2); a3 = fmaf(w1, hi.y, a3);
    a0 = fmaf(w2, lo.y, a0); a1 = fmaf(w2, lo.z, a1); a2 = fmaf(w2, lo.w, a2); a3 = fmaf(w2, hi.x, a3);
    a0 = fmaf(w3, lo.x, a0); a1 = fmaf(w3, lo.y, a1); a2 = fmaf(w3, lo.z, a2); a3 = fmaf(w3, lo.w, a3);
    hi = lo;
    lo = lv4[t + (KC / 4 - 2) - g];
  }
  { // peeled last group (no further load)
    const int g = KC / 4 - 1;
    const float w0 = wp[4 * g + 0], w1 = wp[4 * g + 1],
                w2 = wp[4 * g + 2], w3 = wp[4 * g + 3];
    a0 = fmaf(w0, lo.w, a0); a1 = fmaf(w0, hi.x, a1); a2 = fmaf(w0, hi.y, a2); a3 = fmaf(w0, hi.z, a3);
    a0 = fmaf(w1, lo.z, a0); a1 = fmaf(w1, lo.w, a1); a2 = fmaf(w1, hi.x, a2); a3 = fmaf(w1, hi.y, a3);
    a0 = fmaf(w2, lo.y, a0); a1 = fmaf(w2, lo.z, a1); a2 = fmaf(w2, lo.w, a2); a3 = fmaf(w2, hi.x, a3);
    a0 = fmaf(w3, lo.x, a0); a1 = fmaf(w3, lo.y, a1); a2 = fmaf(w3, lo.z, a2); a3 = fmaf(w3, lo.w, a3);
  }
  float4 res = make_float4(a0, a1, a2, a3);
  reinterpret_cast<float4*>(partial + (size_t)ks * FULL_LEN)[jb / 4 + t] = res;
}

// ---------------- reduce: sum split-K partials, compute S, D, Y ----------------
__global__ __launch_bounds__(256) void reduce_kernel(
    const float* __restrict__ partial, const float* __restrict__ bk,
    float* __restrict__ f, int conv_len, double* __restrict__ sums)
{
  __shared__ float sm[12];
  const int j4 = blockIdx.x * 256 + threadIdx.x;
  const int j = j4 * 4;
  float s = 0.f, d = 0.f, y = 0.f;
  if (j < conv_len) {
    float4 b = reinterpret_cast<const float4*>(bk)[j4];
    y = b.x * b.x + b.y * b.y + b.z * b.z + b.w * b.w;
    if (j < FULL_LEN) {
      float4 acc = make_float4(0.f, 0.f, 0.f, 0.f);
#pragma unroll
      for (int ks = 0; ks < 16; ++ks) {
        float4 p = reinterpret_cast<const float4*>(partial + (size_t)ks * FULL_LEN)[j4];
        acc.x += p.x; acc.y += p.y; acc.z += p.z; acc.w += p.w;
      }
      reinterpret_cast<float4*>(f)[j4] = acc;
      s = acc.x * acc.x + acc.y * acc.y + acc.z * acc.z + acc.w * acc.w;
      d = acc.x * b.x + acc.y * b.y + acc.z * b.z + acc.w * b.w;
    }
  }
  const int lane = threadIdx.x & 63, wid = threadIdx.x >> 6;
  s = waveReduceSum(s); d = waveReduceSum(d); y = waveReduceSum(y);
  if (lane == 0) { sm[wid] = s; sm[4 + wid] = d; sm[8 + wid] = y; }
  __syncthreads();
  if (threadIdx.x == 0) {
    float S = sm[0] + sm[1] + sm[2] + sm[3];
    float D = sm[4] + sm[5] + sm[6] + sm[7];
    float Y = sm[8] + sm[9] + sm[10] + sm[11];
    atomicAdd(&sums[0], (double)S);
    atomicAdd(&sums[1], (double)D);
    atomicAdd(&sums[2], (double)Y);
  }
}

// ---------------- combine: out = relu(a*f + b*bk); optional N = sum(out^2) ----------------
__global__ __launch_bounds__(256) void combine_kernel(
    const float* __restrict__ f, const float* __restrict__ bk,
    float* __restrict__ out, int lenB, const double* __restrict__ sums,
    double* __restrict__ Nacc, int last)
{
  __shared__ float sm[4];
  const float c = 1e-5f;
  const float sc = 0.0031622776601683794f; // sqrt(1e-5)
  const float S = (float)sums[0], D = (float)sums[1], Y = (float)sums[2];
  // euc_to_hyp(total_conv) = beta * f
  const float nf = fmaxf(sqrtf(S), 1e-15f);
  const float scnf = sc * nf;
  const float alpha = tanhf(scnf) / scnf;
  const float n = fmaxf(alpha * nf, 1e-15f);
  const float maxn = (1.0f - 4e-3f) / sc;
  const float beta = (n > maxn) ? (alpha * (maxn / n)) : alpha;
  // mobius_add(beta*f, bk)
  const float x2 = beta * beta * S;
  const float xy = beta * D;
  const float y2 = Y;
  const float cnum = 1.0f + 2.0f * c * xy + c * y2;
  const float cyc_ = 1.0f - c * x2;
  const float den = fmaxf(1.0f + 2.0f * c * xy + c * c * x2 * y2, 1e-15f);
  const float a = cnum * beta / den;
  const float b = cyc_ / den;

  const int j4 = blockIdx.x * 256 + threadIdx.x;
  const int j = j4 * 4;
  float nacc = 0.f;
  if (j < lenB) {
    float4 bv = reinterpret_cast<const float4*>(bk)[j4];
    float4 fv = make_float4(0.f, 0.f, 0.f, 0.f);
    if (j < FULL_LEN) fv = reinterpret_cast<const float4*>(f)[j4];
    float4 o;
    o.x = fmaxf(a * fv.x + b * bv.x, 0.f);
    o.y = fmaxf(a * fv.y + b * bv.y, 0.f);
    o.z = fmaxf(a * fv.z + b * bv.z, 0.f);
    o.w = fmaxf(a * fv.w + b * bv.w, 0.f);
    reinterpret_cast<float4*>(out)[j4] = o;
    nacc = o.x * o.x + o.y * o.y + o.z * o.z + o.w * o.w;
  }
  if (last) {
    const int lane = threadIdx.x & 63, wid = threadIdx.x >> 6;
    nacc = waveReduceSum(nacc);
    if (lane == 0) sm[wid] = nacc;
    __syncthreads();
    if (threadIdx.x == 0)
      atomicAdd(Nacc, (double)(sm[0] + sm[1] + sm[2] + sm[3]));
  }
}

// ---------------- matvec: raw[r] = dot(T[r,:], x) ----------------
__global__ __launch_bounds__(1024) void matvec_kernel(
    const float* __restrict__ T, const float* __restrict__ x,
    float* __restrict__ raw)
{
  __shared__ float sm[16];
  const int r = blockIdx.x;
  const float4* Tr = reinterpret_cast<const float4*>(T + (size_t)r * TOTAL_LEN);
  const float4* x4 = reinterpret_cast<const float4*>(x);
  float s = 0.f;
#pragma unroll 4
  for (int i = threadIdx.x; i < TOTAL_LEN / 4; i += 1024) {
    float4 av = Tr[i], bv = x4[i];
    s = fmaf(av.x, bv.x, s);
    s = fmaf(av.y, bv.y, s);
    s = fmaf(av.z, bv.z, s);
    s = fmaf(av.w, bv.w, s);
  }
  const int lane = threadIdx.x & 63, wid = threadIdx.x >> 6;
  s = waveReduceSum(s);
  if (lane == 0) sm[wid] = s;
  __syncthreads();
  if (threadIdx.x == 0) {
    float tot = 0.f;
#pragma unroll
    for (int i = 0; i < 16; ++i) tot += sm[i];
    raw[r] = tot;
  }
}

// ---------------- final: logmap0 scale + per-element euc_to_hyp + softmax ----------------
__global__ __launch_bounds__(512) void final_kernel(
    const float* __restrict__ raw, const double* __restrict__ Np,
    float* __restrict__ outp)
{
  __shared__ float sm[8];
  const int t = threadIdx.x;
  const float sc = 0.0031622776601683794f;
  const float N = (float)(*Np);
  const float pn = fmaxf(sqrtf(N), 1e-15f);
  float z = sc * pn;
  z = fminf(fmaxf(z, -1.0f + 1e-7f), 1.0f - 1e-7f);
  const float gamma = atanhf(z) / (sc * pn); // logits = gamma * raw
  const float t0 = gamma * raw[t];
  // euc_to_hyp per element (last-dim norm of [512,1] = |x|)
  const float un = fmaxf(fabsf(t0), 1e-15f);
  const float scun = sc * un;
  const float val = (tanhf(scun) / scun) * t0;
  const float nn = fmaxf(fabsf(val), 1e-15f);
  const float maxn = (1.0f - 4e-3f) / sc;
  const float fin = (nn > maxn) ? val * (maxn / nn) : val;
  // softmax over 512
  float wm = waveReduceMax(fin);
  if ((t & 63) == 0) sm[t >> 6] = wm;
  __syncthreads();
  float m = sm[0];
#pragma unroll
  for (int i = 1; i < 8; ++i) m = fmaxf(m, sm[i]);
  const float e = expf(fin - m);
  __syncthreads();
  float ws_ = waveReduceSum(e);
  if ((t & 63) == 0) sm[t >> 6] = ws_;
  __syncthreads();
  float tot = 0.f;
#pragma unroll
  for (int i = 0; i < 8; ++i) tot += sm[i];
  outp[t] = e / tot;
}

// ---------------- launcher ----------------
extern "C" void kernel_launch(void* const* d_in, const int* in_sizes, int n_in,
                              void* d_out, int out_size, void* d_ws, size_t ws_size,
                              hipStream_t stream)
{
  // setup_inputs dict order: hk, w0, bk0, w1, bk1, w2, bk2, w3, bk3, trans_last
  const float* hk = (const float*)d_in[0];
  const float* w[4]  = {(const float*)d_in[1], (const float*)d_in[3],
                        (const float*)d_in[5], (const float*)d_in[7]};
  const float* bk[4] = {(const float*)d_in[2], (const float*)d_in[4],
                        (const float*)d_in[6], (const float*)d_in[8]};
  const float* T = (const float*)d_in[9];
  float* outp = (float*)d_out;

  char* ws = (char*)d_ws;
  double* sums = (double*)ws;                       // 16 doubles; layer i -> sums+3i, N -> sums[12]
  float* raw   = (float*)(ws + 128);                // 512 f32
  float* f     = (float*)(ws + 4096);               // 40960 f32
  float* part  = (float*)(ws + 4096 + 163840);      // 16*40960 f32
  float* outA  = (float*)(ws + 4096 + 163840 + 2621440); // 65536 f32
  float* outB  = outA + TOTAL_LEN;                  // 65536 f32

  hipMemsetAsync(sums, 0, 16 * sizeof(double), stream);

  const int convlens[4] = {40960, 49152, 57344, 65536};
  float* outs[4] = {outA, outB, outA, outB};
  const float* vin = hk;
  for (int i = 0; i < 4; ++i) {
    conv_kernel<<<dim3(40 * 16), dim3(256), 0, stream>>>(vin, w[i], part);
    reduce_kernel<<<dim3(convlens[i] / 1024), dim3(256), 0, stream>>>(
        part, bk[i], f, convlens[i], sums + 3 * i);
    const int lenB = (i == 3) ? TOTAL_LEN : INPUT_SIZE;
    combine_kernel<<<dim3(lenB / 1024), dim3(256), 0, stream>>>(
        f, bk[i], outs[i], lenB, sums + 3 * i, sums + 12, (i == 3) ? 1 : 0);
    vin = outs[i];
  }
  matvec_kernel<<<dim3(NUM_CLASSES), dim3(1024), 0, stream>>>(T, outB, raw);
  final_kernel<<<dim3(1), dim3(512), 0, stream>>>(raw, sums + 12, outp);
}

// Round 2
// 287.807 us; speedup vs baseline: 1.2074x; 1.2074x over previous
//
#include <hip/hip_runtime.h>
#include <math.h>

typedef float f32x4 __attribute__((ext_vector_type(4)));

#define INPUT_SIZE 32768
#define FILTER_LEN 8192
#define FULL_LEN   40960   // 40959 real conv outputs + 1 structural zero
#define NUM_CLASSES 512
#define TOTAL_LEN  65536

constexpr int TO  = 1024;              // outputs per block
constexpr int KC  = 256;               // taps per block (split-K chunk)
constexpr int NKS = FILTER_LEN / KC;   // 32 split-K chunks

// ---------------- reduction helpers ----------------
__device__ __forceinline__ float waveReduceSum(float v) {
#pragma unroll
  for (int o = 32; o > 0; o >>= 1) v += __shfl_down(v, o, 64);
  return v;
}
__device__ __forceinline__ float waveReduceMax(float v) {
#pragma unroll
  for (int o = 32; o > 0; o >>= 1) v = fmaxf(v, __shfl_down(v, o, 64));
  return v;
}

// ---------------- conv: split-K partial convolution ----------------
// f[j] = sum_k w[k] * v[j-k], v zero outside [0, INPUT_SIZE)
// block = (jtile, kchunk): TO outputs, KC taps. 256 thr, 4 outputs/thr.
__global__ __launch_bounds__(256) void conv_kernel(
    const float* __restrict__ v, const float* __restrict__ w,
    float* __restrict__ partial, double* __restrict__ sums, int zero_flag)
{
  __shared__ float lv[TO + KC];  // signal window
  __shared__ float lw[KC];       // filter chunk
  if (zero_flag && blockIdx.x == 0 && threadIdx.x < 16)
    sums[threadIdx.x] = 0.0;
  const int jt = blockIdx.x / NKS;
  const int ks = blockIdx.x % NKS;
  const int jb = jt * TO, kc = ks * KC;
  const int wb = jb - kc - (KC - 1);  // window covers v[wb .. wb+TO+KC-1]
  const int t = threadIdx.x;
  lw[t] = w[kc + t];
  for (int s = t; s < TO + KC; s += 256) {
    int idx = wb + s;
    lv[s] = (idx >= 0 && idx < INPUT_SIZE) ? v[idx] : 0.0f;
  }
  __syncthreads();
  const f32x4* lv4 = reinterpret_cast<const f32x4*>(lv);
  const f32x4* lw4 = reinterpret_cast<const f32x4*>(lw);
  f32x4 acc = {0.f, 0.f, 0.f, 0.f};
  // outputs j0..j0+3, j0 = jb + 4t; tap group g covers w[kc+4g .. kc+4g+3]
  // lv float index for (r, d): 4t + r + KC-1 - 4g - d
#pragma unroll 8
  for (int g = 0; g < KC / 4; ++g) {
    const f32x4 wv = lw4[g];                     // broadcast (uniform addr)
    const f32x4 lo = lv4[t + KC / 4 - 1 - g];    // floats 4t+KC-4-4g .. +3
    const f32x4 hi = lv4[t + KC / 4 - g];        // floats 4t+KC-4g   .. +3
    acc.x = fmaf(wv.x, lo.w, acc.x); acc.y = fmaf(wv.x, hi.x, acc.y);
    acc.z = fmaf(wv.x, hi.y, acc.z); acc.w = fmaf(wv.x, hi.z, acc.w);
    acc.x = fmaf(wv.y, lo.z, acc.x); acc.y = fmaf(wv.y, lo.w, acc.y);
    acc.z = fmaf(wv.y, hi.x, acc.z); acc.w = fmaf(wv.y, hi.y, acc.w);
    acc.x = fmaf(wv.z, lo.y, acc.x); acc.y = fmaf(wv.z, lo.z, acc.y);
    acc.z = fmaf(wv.z, lo.w, acc.z); acc.w = fmaf(wv.z, hi.x, acc.w);
    acc.x = fmaf(wv.w, lo.x, acc.x); acc.y = fmaf(wv.w, lo.y, acc.y);
    acc.z = fmaf(wv.w, lo.z, acc.z); acc.w = fmaf(wv.w, lo.w, acc.w);
  }
  reinterpret_cast<f32x4*>(partial + (size_t)ks * FULL_LEN + jb)[t] = acc;
}

// ---------------- reduce: sum split-K partials, compute S, D, Y ----------------
__global__ __launch_bounds__(256) void reduce_kernel(
    const float* __restrict__ partial, const float* __restrict__ bk,
    float* __restrict__ f, int conv_len, double* __restrict__ sums)
{
  __shared__ float sm[12];
  const int j4 = blockIdx.x * 256 + threadIdx.x;
  const int j = j4 * 4;
  float s = 0.f, d = 0.f, y = 0.f;
  if (j < conv_len) {
    f32x4 b = reinterpret_cast<const f32x4*>(bk)[j4];
    y = b.x * b.x + b.y * b.y + b.z * b.z + b.w * b.w;
    if (j < FULL_LEN) {
      f32x4 acc = {0.f, 0.f, 0.f, 0.f};
#pragma unroll
      for (int ks = 0; ks < NKS; ++ks) {
        f32x4 p = reinterpret_cast<const f32x4*>(partial + (size_t)ks * FULL_LEN)[j4];
        acc.x += p.x; acc.y += p.y; acc.z += p.z; acc.w += p.w;
      }
      reinterpret_cast<f32x4*>(f)[j4] = acc;
      s = acc.x * acc.x + acc.y * acc.y + acc.z * acc.z + acc.w * acc.w;
      d = acc.x * b.x + acc.y * b.y + acc.z * b.z + acc.w * b.w;
    }
  }
  const int lane = threadIdx.x & 63, wid = threadIdx.x >> 6;
  s = waveReduceSum(s); d = waveReduceSum(d); y = waveReduceSum(y);
  if (lane == 0) { sm[wid] = s; sm[4 + wid] = d; sm[8 + wid] = y; }
  __syncthreads();
  if (threadIdx.x == 0) {
    float S = sm[0] + sm[1] + sm[2] + sm[3];
    float D = sm[4] + sm[5] + sm[6] + sm[7];
    float Y = sm[8] + sm[9] + sm[10] + sm[11];
    atomicAdd(&sums[0], (double)S);
    atomicAdd(&sums[1], (double)D);
    atomicAdd(&sums[2], (double)Y);
  }
}

// ---------------- combine: out = relu(a*f + b*bk); optional N = sum(out^2) ----------------
__global__ __launch_bounds__(256) void combine_kernel(
    const float* __restrict__ f, const float* __restrict__ bk,
    float* __restrict__ out, int lenB, const double* __restrict__ sums,
    double* __restrict__ Nacc, int last)
{
  __shared__ float sm[4];
  const float c = 1e-5f;
  const float sc = 0.0031622776601683794f; // sqrt(1e-5)
  const float S = (float)sums[0], D = (float)sums[1], Y = (float)sums[2];
  // euc_to_hyp(total_conv) = beta * f
  const float nf = fmaxf(sqrtf(S), 1e-15f);
  const float scnf = sc * nf;
  const float alpha = tanhf(scnf) / scnf;
  const float n = fmaxf(alpha * nf, 1e-15f);
  const float maxn = (1.0f - 4e-3f) / sc;
  const float beta = (n > maxn) ? (alpha * (maxn / n)) : alpha;
  // mobius_add(beta*f, bk)
  const float x2 = beta * beta * S;
  const float xy = beta * D;
  const float y2 = Y;
  const float cnum = 1.0f + 2.0f * c * xy + c * y2;
  const float cyc_ = 1.0f - c * x2;
  const float den = fmaxf(1.0f + 2.0f * c * xy + c * c * x2 * y2, 1e-15f);
  const float a = cnum * beta / den;
  const float b = cyc_ / den;

  const int j4 = blockIdx.x * 256 + threadIdx.x;
  const int j = j4 * 4;
  float nacc = 0.f;
  if (j < lenB) {
    f32x4 bv = reinterpret_cast<const f32x4*>(bk)[j4];
    f32x4 fv = {0.f, 0.f, 0.f, 0.f};
    if (j < FULL_LEN) fv = reinterpret_cast<const f32x4*>(f)[j4];
    f32x4 o;
    o.x = fmaxf(a * fv.x + b * bv.x, 0.f);
    o.y = fmaxf(a * fv.y + b * bv.y, 0.f);
    o.z = fmaxf(a * fv.z + b * bv.z, 0.f);
    o.w = fmaxf(a * fv.w + b * bv.w, 0.f);
    reinterpret_cast<f32x4*>(out)[j4] = o;
    nacc = o.x * o.x + o.y * o.y + o.z * o.z + o.w * o.w;
  }
  if (last) {
    const int lane = threadIdx.x & 63, wid = threadIdx.x >> 6;
    nacc = waveReduceSum(nacc);
    if (lane == 0) sm[wid] = nacc;
    __syncthreads();
    if (threadIdx.x == 0)
      atomicAdd(Nacc, (double)(sm[0] + sm[1] + sm[2] + sm[3]));
  }
}

// ---------------- matvec: raw[r] = dot(T[r,:], x) ----------------
__global__ __launch_bounds__(1024) void matvec_kernel(
    const float* __restrict__ T, const float* __restrict__ x,
    float* __restrict__ raw)
{
  __shared__ float sm[16];
  const int r = blockIdx.x;
  const f32x4* Tr = reinterpret_cast<const f32x4*>(T + (size_t)r * TOTAL_LEN);
  const f32x4* x4 = reinterpret_cast<const f32x4*>(x);
  float s = 0.f;
#pragma unroll
  for (int it = 0; it < TOTAL_LEN / 4 / 1024; ++it) {
    const int i = it * 1024 + threadIdx.x;
    f32x4 av = __builtin_nontemporal_load(Tr + i);  // streamed, no reuse
    f32x4 bv = x4[i];                               // reused across blocks (L2)
    s = fmaf(av.x, bv.x, s);
    s = fmaf(av.y, bv.y, s);
    s = fmaf(av.z, bv.z, s);
    s = fmaf(av.w, bv.w, s);
  }
  const int lane = threadIdx.x & 63, wid = threadIdx.x >> 6;
  s = waveReduceSum(s);
  if (lane == 0) sm[wid] = s;
  __syncthreads();
  if (threadIdx.x == 0) {
    float tot = 0.f;
#pragma unroll
    for (int i = 0; i < 16; ++i) tot += sm[i];
    raw[r] = tot;
  }
}

// ---------------- final: logmap0 scale + per-element euc_to_hyp + softmax ----------------
__global__ __launch_bounds__(512) void final_kernel(
    const float* __restrict__ raw, const double* __restrict__ Np,
    float* __restrict__ outp)
{
  __shared__ float sm[8];
  const int t = threadIdx.x;
  const float sc = 0.0031622776601683794f;
  const float N = (float)(*Np);
  const float pn = fmaxf(sqrtf(N), 1e-15f);
  float z = sc * pn;
  z = fminf(fmaxf(z, -1.0f + 1e-7f), 1.0f - 1e-7f);
  const float gamma = atanhf(z) / (sc * pn); // logits = gamma * raw
  const float t0 = gamma * raw[t];
  // euc_to_hyp per element (last-dim norm of [512,1] = |x|)
  const float un = fmaxf(fabsf(t0), 1e-15f);
  const float scun = sc * un;
  const float val = (tanhf(scun) / scun) * t0;
  const float nn = fmaxf(fabsf(val), 1e-15f);
  const float maxn = (1.0f - 4e-3f) / sc;
  const float fin = (nn > maxn) ? val * (maxn / nn) : val;
  // softmax over 512
  float wm = waveReduceMax(fin);
  if ((t & 63) == 0) sm[t >> 6] = wm;
  __syncthreads();
  float m = sm[0];
#pragma unroll
  for (int i = 1; i < 8; ++i) m = fmaxf(m, sm[i]);
  const float e = expf(fin - m);
  __syncthreads();
  float ws_ = waveReduceSum(e);
  if ((t & 63) == 0) sm[t >> 6] = ws_;
  __syncthreads();
  float tot = 0.f;
#pragma unroll
  for (int i = 0; i < 8; ++i) tot += sm[i];
  outp[t] = e / tot;
}

// ---------------- launcher ----------------
extern "C" void kernel_launch(void* const* d_in, const int* in_sizes, int n_in,
                              void* d_out, int out_size, void* d_ws, size_t ws_size,
                              hipStream_t stream)
{
  // setup_inputs dict order: hk, w0, bk0, w1, bk1, w2, bk2, w3, bk3, trans_last
  const float* hk = (const float*)d_in[0];
  const float* w[4]  = {(const float*)d_in[1], (const float*)d_in[3],
                        (const float*)d_in[5], (const float*)d_in[7]};
  const float* bk[4] = {(const float*)d_in[2], (const float*)d_in[4],
                        (const float*)d_in[6], (const float*)d_in[8]};
  const float* T = (const float*)d_in[9];
  float* outp = (float*)d_out;

  char* ws = (char*)d_ws;
  double* sums = (double*)ws;                       // 16 doubles; layer i -> sums+3i, N -> sums[12]
  float* raw   = (float*)(ws + 4096);               // 512 f32
  float* f     = (float*)(ws + 8192);               // 40960 f32
  float* part  = (float*)(ws + 8192 + 163840);      // NKS*40960 f32 (5.24 MB)
  float* outA  = (float*)(ws + 8192 + 163840 + NKS * FULL_LEN * 4);
  float* outB  = outA + TOTAL_LEN;

  const int convlens[4] = {40960, 49152, 57344, 65536};
  float* outs[4] = {outA, outB, outA, outB};
  const float* vin = hk;
  for (int i = 0; i < 4; ++i) {
    conv_kernel<<<dim3((FULL_LEN / TO) * NKS), dim3(256), 0, stream>>>(
        vin, w[i], part, sums, (i == 0) ? 1 : 0);
    reduce_kernel<<<dim3(convlens[i] / 1024), dim3(256), 0, stream>>>(
        part, bk[i], f, convlens[i], sums + 3 * i);
    const int lenB = (i == 3) ? TOTAL_LEN : INPUT_SIZE;
    combine_kernel<<<dim3(lenB / 1024), dim3(256), 0, stream>>>(
        f, bk[i], outs[i], lenB, sums + 3 * i, sums + 12, (i == 3) ? 1 : 0);
    vin = outs[i];
  }
  matvec_kernel<<<dim3(NUM_CLASSES), dim3(1024), 0, stream>>>(T, outB, raw);
  final_kernel<<<dim3(1), dim3(512), 0, stream>>>(raw, sums + 12, outp);
}